// Round 11
// baseline (106.763 us; speedup 1.0000x reference)
//
#include <hip/hip_runtime.h>
#include <hip/hip_fp16.h>

// NNUE forward, R11: q8 table + wide gather (uint4/lane, 4 boards/wave).
// R10 finding: q8's 4-line row-instructions ran at 9.1 cy/line vs the
// 5.1 cy/line invariant of >=8-line instructions -> per-instruction floor.
// Fix: one instruction now gathers FOUR boards' rows (16 lanes x 16 B each):
//   instrs/board 64 -> 16, lines/board unchanged (256), access shape
//   identical to the f32 kernel that provenly ran at line rate.
// Tail: barrier-free within-wave (R8 structure; safe without VGPR cap).
// No __launch_bounds__ min-waves (R8 lesson). Single dispatch (R9 lesson).

constexpr int BATCH  = 16384;
constexpr int NNZPB  = 32;
constexpr int NNZ    = BATCH * NNZPB;
constexpr int HIDDEN = 256;
constexpr int FEATSZ = 64 * 64 * 10;                      // 40960

constexpr float QLIM  = 0.0060329f;
constexpr float QS    = QLIM / 127.0f;
constexpr float QSINV = 127.0f / QLIM;

constexpr size_t Q8_BYTES  = (size_t)FEATSZ * 256;        // 10,485,760
constexpr size_t FC1_BYTES = 512 * 32 * 2;                //     32,768
constexpr size_t WS_NEED   = Q8_BYTES + FC1_BYTES;

__device__ __forceinline__ float crelu1(float v) {
    return fminf(fmaxf(v, 0.0f), 1.0f);
}

// 4 bytes of one dword -> 4 f32 fma (v_cvt_f32_ubyte0..3)
__device__ __forceinline__ void dec4(unsigned d, float s, float4& a) {
    a.x = fmaf((float)(d & 0xFFu),         s, a.x);
    a.y = fmaf((float)((d >> 8) & 0xFFu),  s, a.y);
    a.z = fmaf((float)((d >> 16) & 0xFFu), s, a.z);
    a.w = fmaf((float)(d >> 24),           s, a.w);
}

// ---- convert: ft_w f32 -> u8 (bias 128); fc1_w -> fp16 ------------------
__global__ __launch_bounds__(256) void convert_q8(
    const float4* __restrict__ src,
    unsigned int* __restrict__ q8,
    const float*  __restrict__ fc1w,
    __half2*      __restrict__ fc1w16,
    int n4)
{
    const int gid    = blockIdx.x * 256 + threadIdx.x;
    const int stride = gridDim.x * 256;
    for (int i = gid; i < n4; i += stride) {
        const float4 v = src[i];
        int q0 = (int)lrintf(v.x * QSINV) + 128;
        int q1 = (int)lrintf(v.y * QSINV) + 128;
        int q2 = (int)lrintf(v.z * QSINV) + 128;
        int q3 = (int)lrintf(v.w * QSINV) + 128;
        q0 = min(max(q0, 0), 255); q1 = min(max(q1, 0), 255);
        q2 = min(max(q2, 0), 255); q3 = min(max(q3, 0), 255);
        q8[i] = (unsigned)q0 | ((unsigned)q1 << 8) |
                ((unsigned)q2 << 16) | ((unsigned)q3 << 24);
    }
    for (int j = gid; j < 8192; j += stride)
        fc1w16[j] = __floats2half2_rn(fc1w[2 * j], fc1w[2 * j + 1]);
}

// ---- fused kernel: wide q8 gather + barrier-free tail --------------------
// block = 256 = 4 waves; wave = 4 boards. lane = (q = lane>>4: board sub,
// p = lane&15: col chunk of 16). One VMEM instr = 4 boards' rows = 16 lines.
__global__ void nnue_fwd_q8w(
    const int*    __restrict__ wfeat,
    const float*  __restrict__ wval,
    const int*    __restrict__ bfeat,
    const float*  __restrict__ bval,
    const unsigned char* __restrict__ q8,   // [FEATSZ][256]
    const float4* __restrict__ ftb,         // [64] float4
    const __half* __restrict__ fc1w16,      // [512][32] fp16
    const float*  __restrict__ fc1b,
    const float*  __restrict__ fc2w,        // [32][32]
    const float*  __restrict__ fc2b,
    const float*  __restrict__ fc3w,        // [32]
    const float*  __restrict__ fc3b,
    float*        __restrict__ out)
{
    __shared__ float xs[16][512];    // 16 boards/block
    __shared__ float h1s[16][32];

    const int tid  = threadIdx.x;
    const int w    = tid >> 6;
    const int lane = tid & 63;
    const int q    = lane >> 4;      // board sub-index 0..3
    const int p    = lane & 15;      // col chunk: cols [16p, 16p+16)
    const int b0 = __builtin_amdgcn_readfirstlane((int)blockIdx.x * 16 + w * 4);

    const int*   wip0 = wfeat + (b0 + 0) * NNZPB;
    const int*   wip1 = wfeat + (b0 + 1) * NNZPB;
    const int*   wip2 = wfeat + (b0 + 2) * NNZPB;
    const int*   wip3 = wfeat + (b0 + 3) * NNZPB;
    const float* wvp0 = wval  + (b0 + 0) * NNZPB;
    const float* wvp1 = wval  + (b0 + 1) * NNZPB;
    const float* wvp2 = wval  + (b0 + 2) * NNZPB;
    const float* wvp3 = wval  + (b0 + 3) * NNZPB;
    const int*   bip0 = bfeat + (b0 + 0) * NNZPB;
    const int*   bip1 = bfeat + (b0 + 1) * NNZPB;
    const int*   bip2 = bfeat + (b0 + 2) * NNZPB;
    const int*   bip3 = bfeat + (b0 + 3) * NNZPB;
    const float* bvp0 = bval  + (b0 + 0) * NNZPB;
    const float* bvp1 = bval  + (b0 + 1) * NNZPB;
    const float* bvp2 = bval  + (b0 + 2) * NNZPB;
    const float* bvp3 = bval  + (b0 + 3) * NNZPB;

    float4 aw[4] = {{0,0,0,0},{0,0,0,0},{0,0,0,0},{0,0,0,0}};
    float4 ab[4] = {{0,0,0,0},{0,0,0,0},{0,0,0,0},{0,0,0,0}};
    float  ssw = 0.f, ssb = 0.f;

    const int rowoff = p << 4;       // byte offset of this lane's 16B chunk

    #pragma unroll 8
    for (int k = 0; k < NNZPB; ++k) {
        // wave-uniform scalar loads (s_load), per-lane select via cndmask
        const int   f0w = wip0[k], f1w = wip1[k], f2w = wip2[k], f3w = wip3[k];
        const float v0w = wvp0[k], v1w = wvp1[k], v2w = wvp2[k], v3w = wvp3[k];
        const int   f0b = bip0[k], f1b = bip1[k], f2b = bip2[k], f3b = bip3[k];
        const float v0b = bvp0[k], v1b = bvp1[k], v2b = bvp2[k], v3b = bvp3[k];

        const int   fw = (q == 0) ? f0w : (q == 1) ? f1w : (q == 2) ? f2w : f3w;
        const float vw = (q == 0) ? v0w : (q == 1) ? v1w : (q == 2) ? v2w : v3w;
        const int   fb = (q == 0) ? f0b : (q == 1) ? f1b : (q == 2) ? f2b : f3b;
        const float vb = (q == 0) ? v0b : (q == 1) ? v1b : (q == 2) ? v2b : v3b;

        const uint4 HW = *reinterpret_cast<const uint4*>(
            q8 + (size_t)fw * 256 + rowoff);
        const uint4 HB = *reinterpret_cast<const uint4*>(
            q8 + (size_t)fb * 256 + rowoff);

        ssw += vw;  ssb += vb;
        const float sw = QS * vw;
        const float sb = QS * vb;

        dec4(HW.x, sw, aw[0]); dec4(HW.y, sw, aw[1]);
        dec4(HW.z, sw, aw[2]); dec4(HW.w, sw, aw[3]);
        dec4(HB.x, sb, ab[0]); dec4(HB.y, sb, ab[1]);
        dec4(HB.z, sb, ab[2]); dec4(HB.w, sb, ab[3]);
    }

    // epilogue: remove +128 bias exactly, add ft bias, crelu, stash in LDS
    const int bsub = w * 4 + q;
    const float corw = 128.0f * QS * ssw;
    const float corb = 128.0f * QS * ssb;
    float4* xw4 = reinterpret_cast<float4*>(xs[bsub]);
    #pragma unroll
    for (int j = 0; j < 4; ++j) {
        const float4 bias = ftb[4 * p + j];
        float4 cw, cb;
        cw.x = crelu1(aw[j].x - corw + bias.x);
        cw.y = crelu1(aw[j].y - corw + bias.y);
        cw.z = crelu1(aw[j].z - corw + bias.z);
        cw.w = crelu1(aw[j].w - corw + bias.w);
        cb.x = crelu1(ab[j].x - corb + bias.x);
        cb.y = crelu1(ab[j].y - corb + bias.y);
        cb.z = crelu1(ab[j].z - corb + bias.z);
        cb.w = crelu1(ab[j].w - corb + bias.w);
        xw4[4 * p + j]      = cw;
        xw4[64 + 4 * p + j] = cb;
    }

    // ---- tail: entirely within-wave, no __syncthreads ----
    const int o = lane & 31;
    const int h = lane >> 5;

    #pragma unroll
    for (int bb = 0; bb < 4; ++bb) {
        const int bs = w * 4 + bb;

        // fc1: (o, h) half-dot over 256 inputs, fp16 weights (L1-resident)
        const float4* xr = reinterpret_cast<const float4*>(&xs[bs][h * 256]);
        const __half* wr = fc1w16 + (h * 256) * 32 + o;
        float s = 0.0f;
        #pragma unroll 8
        for (int i4 = 0; i4 < 64; ++i4) {
            const float4 xv = xr[i4];
            s = fmaf(xv.x, __half2float(wr[(i4 * 4 + 0) * 32]), s);
            s = fmaf(xv.y, __half2float(wr[(i4 * 4 + 1) * 32]), s);
            s = fmaf(xv.z, __half2float(wr[(i4 * 4 + 2) * 32]), s);
            s = fmaf(xv.w, __half2float(wr[(i4 * 4 + 3) * 32]), s);
        }
        const float tot = s + __shfl(s, lane ^ 32);
        if (lane < 32) h1s[bs][o] = crelu1(tot + fc1b[o]);

        // fc2 (redundant across halves; LDS broadcast reads, same wave)
        float a2 = fc2b[o];
        #pragma unroll
        for (int i = 0; i < 32; ++i)
            a2 = fmaf(h1s[bs][i], fc2w[i * 32 + o], a2);

        // fc3 shuffle-reduce over lanes 0..31
        float t = crelu1(a2) * fc3w[o];
        t += __shfl_xor(t, 1);
        t += __shfl_xor(t, 2);
        t += __shfl_xor(t, 4);
        t += __shfl_xor(t, 8);
        t += __shfl_xor(t, 16);
        if (lane == 0) out[b0 + bb] = t + fc3b[0];
    }
}

// ---- fallback: fully f32 fused (no workspace needed) --------------------
__global__ __launch_bounds__(256) void nnue_fwd_f32(
    const int*    __restrict__ wfeat,
    const float*  __restrict__ wval,
    const int*    __restrict__ bfeat,
    const float*  __restrict__ bval,
    const float4* __restrict__ ftw,
    const float4* __restrict__ ftb,
    const float*  __restrict__ fc1w,
    const float*  __restrict__ fc1b,
    const float*  __restrict__ fc2w,
    const float*  __restrict__ fc2b,
    const float*  __restrict__ fc3w,
    const float*  __restrict__ fc3b,
    float*        __restrict__ out)
{
    __shared__ float x[4][512];
    __shared__ float p1[4][2][32];
    __shared__ float h1[4][32];
    __shared__ float h2[4][32];

    const int tid  = threadIdx.x;
    const int w    = tid >> 6;
    const int lane = tid & 63;
    const int board = __builtin_amdgcn_readfirstlane((int)(blockIdx.x << 2) + w);

    const int*   wip = wfeat + board * NNZPB;
    const float* wvp = wval  + board * NNZPB;
    const int*   bip = bfeat + board * NNZPB;
    const float* bvp = bval  + board * NNZPB;

    float4 accw = ftb[lane];
    float4 accb = accw;

    #pragma unroll
    for (int k = 0; k < NNZPB; ++k) {
        const int   fw = wip[k];
        const float vw = wvp[k];
        const int   fb = bip[k];
        const float vb = bvp[k];
        const float4 rw = ftw[fw * 64 + lane];
        const float4 rb = ftw[fb * 64 + lane];
        accw.x = fmaf(rw.x, vw, accw.x); accw.y = fmaf(rw.y, vw, accw.y);
        accw.z = fmaf(rw.z, vw, accw.z); accw.w = fmaf(rw.w, vw, accw.w);
        accb.x = fmaf(rb.x, vb, accb.x); accb.y = fmaf(rb.y, vb, accb.y);
        accb.z = fmaf(rb.z, vb, accb.z); accb.w = fmaf(rb.w, vb, accb.w);
    }

    {
        float4 cw, cb;
        cw.x = crelu1(accw.x); cw.y = crelu1(accw.y);
        cw.z = crelu1(accw.z); cw.w = crelu1(accw.w);
        cb.x = crelu1(accb.x); cb.y = crelu1(accb.y);
        cb.z = crelu1(accb.z); cb.w = crelu1(accb.w);
        reinterpret_cast<float4*>(x[w])[lane]      = cw;
        reinterpret_cast<float4*>(x[w])[64 + lane] = cb;
    }
    __syncthreads();

    {
        const int o = lane & 31;
        const int h = lane >> 5;
        const float4* xr = reinterpret_cast<const float4*>(&x[w][h * 256]);
        const float*  wr = fc1w + (h * 256) * 32 + o;
        float s = 0.0f;
        #pragma unroll 16
        for (int i4 = 0; i4 < 64; ++i4) {
            const float4 xv = xr[i4];
            s = fmaf(xv.x, wr[(i4 * 4 + 0) * 32], s);
            s = fmaf(xv.y, wr[(i4 * 4 + 1) * 32], s);
            s = fmaf(xv.z, wr[(i4 * 4 + 2) * 32], s);
            s = fmaf(xv.w, wr[(i4 * 4 + 3) * 32], s);
        }
        p1[w][h][o] = s;
    }
    __syncthreads();

    if (lane < 32) {
        const float v = p1[w][0][lane] + p1[w][1][lane] + fc1b[lane];
        h1[w][lane] = crelu1(v);
    }
    __syncthreads();

    if (lane < 32) {
        float s = fc2b[lane];
        #pragma unroll
        for (int i = 0; i < 32; ++i)
            s = fmaf(h1[w][i], fc2w[i * 32 + lane], s);
        h2[w][lane] = crelu1(s);
    }
    __syncthreads();

    if (lane == 0) {
        float s = fc3b[0];
        #pragma unroll
        for (int i = 0; i < 32; ++i)
            s = fmaf(h2[w][i], fc3w[i], s);
        out[board] = s;
    }
}

extern "C" void kernel_launch(void* const* d_in, const int* in_sizes, int n_in,
                              void* d_out, int out_size, void* d_ws, size_t ws_size,
                              hipStream_t stream) {
    const int*   w_indices = (const int*)  d_in[0];
    const float* w_values  = (const float*)d_in[1];
    const int*   b_indices = (const int*)  d_in[2];
    const float* b_values  = (const float*)d_in[3];
    const float* ft_w      = (const float*)d_in[4];
    const float* ft_b      = (const float*)d_in[5];
    const float* fc1_w     = (const float*)d_in[6];
    const float* fc1_b     = (const float*)d_in[7];
    const float* fc2_w     = (const float*)d_in[8];
    const float* fc2_b     = (const float*)d_in[9];
    const float* fc3_w     = (const float*)d_in[10];
    const float* fc3_b     = (const float*)d_in[11];
    float* out = (float*)d_out;

    const int* wfeat = w_indices + NNZ;
    const int* bfeat = b_indices + NNZ;

    if (ws_size >= WS_NEED) {
        unsigned char* q8 = (unsigned char*)d_ws;
        __half* fc1w16    = (__half*)(q8 + Q8_BYTES);

        convert_q8<<<2048, 256, 0, stream>>>(
            (const float4*)ft_w, (unsigned int*)q8,
            fc1_w, (__half2*)fc1w16,
            FEATSZ * HIDDEN / 4);

        nnue_fwd_q8w<<<BATCH / 16, 256, 0, stream>>>(
            wfeat, w_values, bfeat, b_values,
            q8, (const float4*)ft_b,
            fc1w16, fc1_b, fc2_w, fc2_b, fc3_w, fc3_b, out);
    } else {
        nnue_fwd_f32<<<BATCH / 4, 256, 0, stream>>>(
            wfeat, w_values, bfeat, b_values,
            (const float4*)ft_w, (const float4*)ft_b,
            fc1_w, fc1_b, fc2_w, fc2_b, fc3_w, fc3_b, out);
    }
}

// Round 12
// 101.324 us; speedup vs baseline: 1.0537x; 1.0537x over previous
//
#include <hip/hip_runtime.h>
#include <hip/hip_fp16.h>

// NNUE forward, R12: R10 (q8 gather, 62us proven) + transposed vectorized
// FC weight loads.
// R11 post-mortem re-fit: total VMEM instrs/board = 320, of which 256 are
// fc1's scalar stride-32 weight loads (L1-hit but each occupies the VMEM
// issue pipe ~7cy). Fix: fc1 weights transposed to [32 out][512 in] fp16 ->
// thread (o,h) reads contiguously, 32 x uint4 (8 halfs) instead of 256
// scalar loads. fc2 transposed too ([32][32] f32 -> 8 x float4).
// VMEM instrs/board: 320 -> ~110. Gather untouched (R10 shape).
// No __launch_bounds__ min-waves (R8), single dispatch (R9), barriers kept
// (R11: barrier-free bought nothing).

constexpr int BATCH  = 16384;
constexpr int NNZPB  = 32;
constexpr int NNZ    = BATCH * NNZPB;
constexpr int HIDDEN = 256;
constexpr int FEATSZ = 64 * 64 * 10;                      // 40960

constexpr float QLIM  = 0.0060329f;
constexpr float QS    = QLIM / 127.0f;
constexpr float QSINV = 127.0f / QLIM;

constexpr size_t Q8_BYTES   = (size_t)FEATSZ * 256;       // 10,485,760
constexpr size_t FC1T_BYTES = 512 * 32 * 2;               // 32,768 (fp16 T)
constexpr size_t FC2T_BYTES = 32 * 32 * 4;                // 4,096  (f32 T)
constexpr size_t WS_NEED    = Q8_BYTES + FC1T_BYTES + FC2T_BYTES;

__device__ __forceinline__ float crelu1(float v) {
    return fminf(fmaxf(v, 0.0f), 1.0f);
}

// ---- convert: ft_w -> u8(+128); fc1_w -> fp16 transposed; fc2_w -> f32 T --
__global__ __launch_bounds__(256) void convert_q8(
    const float4* __restrict__ src,      // ft_w, n4 float4s
    unsigned int* __restrict__ q8,
    const float*  __restrict__ fc1w,     // [512][32]
    __half*       __restrict__ fc1wT,    // [32][512] fp16
    const float*  __restrict__ fc2w,     // [32][32]
    float*        __restrict__ fc2wT,    // [32][32] transposed
    int n4)
{
    const int gid    = blockIdx.x * 256 + threadIdx.x;
    const int stride = gridDim.x * 256;
    for (int i = gid; i < n4; i += stride) {
        const float4 v = src[i];
        int q0 = (int)lrintf(v.x * QSINV) + 128;
        int q1 = (int)lrintf(v.y * QSINV) + 128;
        int q2 = (int)lrintf(v.z * QSINV) + 128;
        int q3 = (int)lrintf(v.w * QSINV) + 128;
        q0 = min(max(q0, 0), 255); q1 = min(max(q1, 0), 255);
        q2 = min(max(q2, 0), 255); q3 = min(max(q3, 0), 255);
        q8[i] = (unsigned)q0 | ((unsigned)q1 << 8) |
                ((unsigned)q2 << 16) | ((unsigned)q3 << 24);
    }
    // fc1 transpose: fc1wT[o*512 + i] = fc1w[i*32 + o]
    for (int j = gid; j < 512 * 32; j += stride) {
        const int o = j >> 9;          // j / 512
        const int i = j & 511;         // j % 512
        fc1wT[j] = __float2half(fc1w[i * 32 + o]);
    }
    // fc2 transpose: fc2wT[o*32 + i] = fc2w[i*32 + o]
    for (int j = gid; j < 32 * 32; j += stride) {
        const int o = j >> 5;
        const int i = j & 31;
        fc2wT[j] = fc2w[i * 32 + o];
    }
}

// ---- fused kernel: q8 gather + crelu + fc1(T,fp16) + fc2(T) + fc3 --------
// block = 256 thr = 4 waves = 4 boards; lane owns cols [4*lane, 4*lane+4).
__global__ void nnue_fwd_q8(
    const int*    __restrict__ wfeat,
    const float*  __restrict__ wval,
    const int*    __restrict__ bfeat,
    const float*  __restrict__ bval,
    const unsigned char* __restrict__ q8,   // [FEATSZ][256]
    const float4* __restrict__ ftb,         // [64] float4
    const __half* __restrict__ fc1wT,       // [32][512] fp16
    const float*  __restrict__ fc1b,
    const float*  __restrict__ fc2wT,       // [32][32] transposed
    const float*  __restrict__ fc2b,
    const float*  __restrict__ fc3w,        // [32]
    const float*  __restrict__ fc3b,
    float*        __restrict__ out)
{
    __shared__ float x[4][2 * HIDDEN];
    __shared__ float p1[4][2][32];
    __shared__ float h1[4][32];
    __shared__ float h2[4][32];

    const int tid  = threadIdx.x;
    const int w    = tid >> 6;
    const int lane = tid & 63;
    const int board = __builtin_amdgcn_readfirstlane((int)(blockIdx.x << 2) + w);

    const int*   wip = wfeat + board * NNZPB;   // wave-uniform -> s_load
    const float* wvp = wval  + board * NNZPB;
    const int*   bip = bfeat + board * NNZPB;
    const float* bvp = bval  + board * NNZPB;

    const int hoff = lane * 4;                  // dword offset in 256-B row

    float4 accw = {0.f, 0.f, 0.f, 0.f};
    float4 accb = {0.f, 0.f, 0.f, 0.f};
    float  sumw = 0.f, sumb = 0.f;

    #pragma unroll
    for (int k = 0; k < NNZPB; ++k) {
        const int   fw = wip[k];
        const float vw = wvp[k];
        const int   fb = bip[k];
        const float vb = bvp[k];
        const unsigned Hw = *reinterpret_cast<const unsigned*>(
            q8 + (size_t)fw * 256 + hoff);
        const unsigned Hb = *reinterpret_cast<const unsigned*>(
            q8 + (size_t)fb * 256 + hoff);

        const float svw = QS * vw;
        const float svb = QS * vb;
        sumw += vw;
        sumb += vb;

        // (float)((H>>8k)&0xFF) -> v_cvt_f32_ubyte{0..3}
        accw.x = fmaf((float)(Hw & 0xFFu),         svw, accw.x);
        accw.y = fmaf((float)((Hw >> 8) & 0xFFu),  svw, accw.y);
        accw.z = fmaf((float)((Hw >> 16) & 0xFFu), svw, accw.z);
        accw.w = fmaf((float)(Hw >> 24),           svw, accw.w);
        accb.x = fmaf((float)(Hb & 0xFFu),         svb, accb.x);
        accb.y = fmaf((float)((Hb >> 8) & 0xFFu),  svb, accb.y);
        accb.z = fmaf((float)((Hb >> 16) & 0xFFu), svb, accb.z);
        accb.w = fmaf((float)(Hb >> 24),           svb, accb.w);
    }

    // remove the +128 encoding bias exactly, add ft bias, crelu
    const float corw = 128.0f * QS * sumw;
    const float corb = 128.0f * QS * sumb;
    const float4 bias = ftb[lane];
    {
        float4 cw, cb;
        cw.x = crelu1(accw.x - corw + bias.x); cw.y = crelu1(accw.y - corw + bias.y);
        cw.z = crelu1(accw.z - corw + bias.z); cw.w = crelu1(accw.w - corw + bias.w);
        cb.x = crelu1(accb.x - corb + bias.x); cb.y = crelu1(accb.y - corb + bias.y);
        cb.z = crelu1(accb.z - corb + bias.z); cb.w = crelu1(accb.w - corb + bias.w);
        reinterpret_cast<float4*>(x[w])[lane]      = cw;
        reinterpret_cast<float4*>(x[w])[64 + lane] = cb;
    }
    __syncthreads();

    // fc1: thread (o = lane&31, h = lane>>5) does a 256-elem dot.
    // Weights CONTIGUOUS: fc1wT + o*512 + h*256, 32 x uint4 (8 halfs each).
    {
        const int o = lane & 31;
        const int h = lane >> 5;
        const float4* xr = reinterpret_cast<const float4*>(&x[w][h * HIDDEN]);
        const uint4*  wr = reinterpret_cast<const uint4*>(
            fc1wT + (o << 9) + (h << 8));
        float s = 0.0f;
        #pragma unroll 8
        for (int i4 = 0; i4 < 32; ++i4) {
            const uint4  wq = wr[i4];
            const float4 x0 = xr[2 * i4];
            const float4 x1 = xr[2 * i4 + 1];
            const float2 w0 = __half22float2(*reinterpret_cast<const __half2*>(&wq.x));
            const float2 w1 = __half22float2(*reinterpret_cast<const __half2*>(&wq.y));
            const float2 w2 = __half22float2(*reinterpret_cast<const __half2*>(&wq.z));
            const float2 w3 = __half22float2(*reinterpret_cast<const __half2*>(&wq.w));
            s = fmaf(x0.x, w0.x, s); s = fmaf(x0.y, w0.y, s);
            s = fmaf(x0.z, w1.x, s); s = fmaf(x0.w, w1.y, s);
            s = fmaf(x1.x, w2.x, s); s = fmaf(x1.y, w2.y, s);
            s = fmaf(x1.z, w3.x, s); s = fmaf(x1.w, w3.y, s);
        }
        p1[w][h][o] = s;
    }
    __syncthreads();

    if (lane < 32) {
        const float v = p1[w][0][lane] + p1[w][1][lane] + fc1b[lane];
        h1[w][lane] = crelu1(v);
    }
    __syncthreads();

    // fc2: lane o reads its transposed row contiguously (8 x float4)
    if (lane < 32) {
        const float4* w2 = reinterpret_cast<const float4*>(fc2wT + (lane << 5));
        float s = fc2b[lane];
        #pragma unroll
        for (int i4 = 0; i4 < 8; ++i4) {
            const float4 wq = w2[i4];
            s = fmaf(h1[w][4 * i4 + 0], wq.x, s);
            s = fmaf(h1[w][4 * i4 + 1], wq.y, s);
            s = fmaf(h1[w][4 * i4 + 2], wq.z, s);
            s = fmaf(h1[w][4 * i4 + 3], wq.w, s);
        }
        h2[w][lane] = crelu1(s);
    }
    __syncthreads();

    if (lane == 0) {
        float s = fc3b[0];
        #pragma unroll
        for (int i = 0; i < 32; ++i)
            s = fmaf(h2[w][i], fc3w[i], s);
        out[board] = s;
    }
}

// ---- fallback: fully f32 fused (no workspace needed) --------------------
__global__ __launch_bounds__(256) void nnue_fwd_f32(
    const int*    __restrict__ wfeat,
    const float*  __restrict__ wval,
    const int*    __restrict__ bfeat,
    const float*  __restrict__ bval,
    const float4* __restrict__ ftw,
    const float4* __restrict__ ftb,
    const float*  __restrict__ fc1w,
    const float*  __restrict__ fc1b,
    const float*  __restrict__ fc2w,
    const float*  __restrict__ fc2b,
    const float*  __restrict__ fc3w,
    const float*  __restrict__ fc3b,
    float*        __restrict__ out)
{
    __shared__ float x[4][512];
    __shared__ float p1[4][2][32];
    __shared__ float h1[4][32];
    __shared__ float h2[4][32];

    const int tid  = threadIdx.x;
    const int w    = tid >> 6;
    const int lane = tid & 63;
    const int board = __builtin_amdgcn_readfirstlane((int)(blockIdx.x << 2) + w);

    const int*   wip = wfeat + board * NNZPB;
    const float* wvp = wval  + board * NNZPB;
    const int*   bip = bfeat + board * NNZPB;
    const float* bvp = bval  + board * NNZPB;

    float4 accw = ftb[lane];
    float4 accb = accw;

    #pragma unroll
    for (int k = 0; k < NNZPB; ++k) {
        const int   fw = wip[k];
        const float vw = wvp[k];
        const int   fb = bip[k];
        const float vb = bvp[k];
        const float4 rw = ftw[fw * 64 + lane];
        const float4 rb = ftw[fb * 64 + lane];
        accw.x = fmaf(rw.x, vw, accw.x); accw.y = fmaf(rw.y, vw, accw.y);
        accw.z = fmaf(rw.z, vw, accw.z); accw.w = fmaf(rw.w, vw, accw.w);
        accb.x = fmaf(rb.x, vb, accb.x); accb.y = fmaf(rb.y, vb, accb.y);
        accb.z = fmaf(rb.z, vb, accb.z); accb.w = fmaf(rb.w, vb, accb.w);
    }

    {
        float4 cw, cb;
        cw.x = crelu1(accw.x); cw.y = crelu1(accw.y);
        cw.z = crelu1(accw.z); cw.w = crelu1(accw.w);
        cb.x = crelu1(accb.x); cb.y = crelu1(accb.y);
        cb.z = crelu1(accb.z); cb.w = crelu1(accb.w);
        reinterpret_cast<float4*>(x[w])[lane]      = cw;
        reinterpret_cast<float4*>(x[w])[64 + lane] = cb;
    }
    __syncthreads();

    {
        const int o = lane & 31;
        const int h = lane >> 5;
        const float4* xr = reinterpret_cast<const float4*>(&x[w][h * 256]);
        const float*  wr = fc1w + (h * 256) * 32 + o;
        float s = 0.0f;
        #pragma unroll 16
        for (int i4 = 0; i4 < 64; ++i4) {
            const float4 xv = xr[i4];
            s = fmaf(xv.x, wr[(i4 * 4 + 0) * 32], s);
            s = fmaf(xv.y, wr[(i4 * 4 + 1) * 32], s);
            s = fmaf(xv.z, wr[(i4 * 4 + 2) * 32], s);
            s = fmaf(xv.w, wr[(i4 * 4 + 3) * 32], s);
        }
        p1[w][h][o] = s;
    }
    __syncthreads();

    if (lane < 32) {
        const float v = p1[w][0][lane] + p1[w][1][lane] + fc1b[lane];
        h1[w][lane] = crelu1(v);
    }
    __syncthreads();

    if (lane < 32) {
        float s = fc2b[lane];
        #pragma unroll
        for (int i = 0; i < 32; ++i)
            s = fmaf(h1[w][i], fc2w[i * 32 + lane], s);
        h2[w][lane] = crelu1(s);
    }
    __syncthreads();

    if (lane == 0) {
        float s = fc3b[0];
        #pragma unroll
        for (int i = 0; i < 32; ++i)
            s = fmaf(h2[w][i], fc3w[i], s);
        out[board] = s;
    }
}

extern "C" void kernel_launch(void* const* d_in, const int* in_sizes, int n_in,
                              void* d_out, int out_size, void* d_ws, size_t ws_size,
                              hipStream_t stream) {
    const int*   w_indices = (const int*)  d_in[0];
    const float* w_values  = (const float*)d_in[1];
    const int*   b_indices = (const int*)  d_in[2];
    const float* b_values  = (const float*)d_in[3];
    const float* ft_w      = (const float*)d_in[4];
    const float* ft_b      = (const float*)d_in[5];
    const float* fc1_w     = (const float*)d_in[6];
    const float* fc1_b     = (const float*)d_in[7];
    const float* fc2_w     = (const float*)d_in[8];
    const float* fc2_b     = (const float*)d_in[9];
    const float* fc3_w     = (const float*)d_in[10];
    const float* fc3_b     = (const float*)d_in[11];
    float* out = (float*)d_out;

    const int* wfeat = w_indices + NNZ;
    const int* bfeat = b_indices + NNZ;

    if (ws_size >= WS_NEED) {
        unsigned char* q8 = (unsigned char*)d_ws;
        __half* fc1wT     = (__half*)(q8 + Q8_BYTES);
        float*  fc2wT     = (float*)(q8 + Q8_BYTES + FC1T_BYTES);

        convert_q8<<<2048, 256, 0, stream>>>(
            (const float4*)ft_w, (unsigned int*)q8,
            fc1_w, fc1wT, fc2_w, fc2wT,
            FEATSZ * HIDDEN / 4);

        nnue_fwd_q8<<<BATCH / 4, 256, 0, stream>>>(
            wfeat, w_values, bfeat, b_values,
            q8, (const float4*)ft_b,
            fc1wT, fc1_b, fc2wT, fc2_b, fc3_w, fc3_b, out);
    } else {
        nnue_fwd_f32<<<BATCH / 4, 256, 0, stream>>>(
            wfeat, w_values, bfeat, b_values,
            (const float4*)ft_w, (const float4*)ft_b,
            fc1_w, fc1_b, fc2_w, fc2_b, fc3_w, fc3_b, out);
    }
}

// Round 13
// 96.717 us; speedup vs baseline: 1.1039x; 1.0476x over previous
//
#include <hip/hip_runtime.h>
#include <hip/hip_fp16.h>

// NNUE forward, R13: q8 gather with FORCED load-ILP + transposed FC weights.
// R12 post-mortem: transposing fc1 weights cut VMEM instrs 3x but let the
// register allocator drop to 32 VGPRs -> gather serialized (62->94us).
// Fix: two-phase gather, fully unrolled -- phase 1 issues all 64 table loads
// into explicit register arrays Hw[32]/Hb[32] (static indices -> registers),
// phase 2 consumes. This structurally requires ~64 VGPRs of in-flight loads;
// the allocator cannot serialize it. Occupancy drops -- proven irrelevant
// (R6: 27% occ same speed); in-flight lines/wave is the lever.
// Keep: q8 table (R10), transposed fp16 fc1 / f32 fc2 (R12), fused tail,
// single dispatch, no launch_bounds min-waves.

constexpr int BATCH  = 16384;
constexpr int NNZPB  = 32;
constexpr int NNZ    = BATCH * NNZPB;
constexpr int HIDDEN = 256;
constexpr int FEATSZ = 64 * 64 * 10;                      // 40960

constexpr float QLIM  = 0.0060329f;
constexpr float QS    = QLIM / 127.0f;
constexpr float QSINV = 127.0f / QLIM;

constexpr size_t Q8_BYTES   = (size_t)FEATSZ * 256;       // 10,485,760
constexpr size_t FC1T_BYTES = 512 * 32 * 2;               // 32,768
constexpr size_t FC2T_BYTES = 32 * 32 * 4;                // 4,096
constexpr size_t WS_NEED    = Q8_BYTES + FC1T_BYTES + FC2T_BYTES;

__device__ __forceinline__ float crelu1(float v) {
    return fminf(fmaxf(v, 0.0f), 1.0f);
}

__device__ __forceinline__ void dec4(unsigned d, float s, float4& a) {
    a.x = fmaf((float)(d & 0xFFu),         s, a.x);
    a.y = fmaf((float)((d >> 8) & 0xFFu),  s, a.y);
    a.z = fmaf((float)((d >> 16) & 0xFFu), s, a.z);
    a.w = fmaf((float)(d >> 24),           s, a.w);
}

// ---- convert: ft_w -> u8(+128); fc1_w -> fp16 T; fc2_w -> f32 T ----------
__global__ __launch_bounds__(256) void convert_q8(
    const float4* __restrict__ src,
    unsigned int* __restrict__ q8,
    const float*  __restrict__ fc1w,     // [512][32]
    __half*       __restrict__ fc1wT,    // [32][512] fp16
    const float*  __restrict__ fc2w,     // [32][32]
    float*        __restrict__ fc2wT,    // [32][32] transposed
    int n4)
{
    const int gid    = blockIdx.x * 256 + threadIdx.x;
    const int stride = gridDim.x * 256;
    for (int i = gid; i < n4; i += stride) {
        const float4 v = src[i];
        int q0 = (int)lrintf(v.x * QSINV) + 128;
        int q1 = (int)lrintf(v.y * QSINV) + 128;
        int q2 = (int)lrintf(v.z * QSINV) + 128;
        int q3 = (int)lrintf(v.w * QSINV) + 128;
        q0 = min(max(q0, 0), 255); q1 = min(max(q1, 0), 255);
        q2 = min(max(q2, 0), 255); q3 = min(max(q3, 0), 255);
        q8[i] = (unsigned)q0 | ((unsigned)q1 << 8) |
                ((unsigned)q2 << 16) | ((unsigned)q3 << 24);
    }
    for (int j = gid; j < 512 * 32; j += stride) {
        const int o = j >> 9;
        const int i = j & 511;
        fc1wT[j] = __float2half(fc1w[i * 32 + o]);
    }
    for (int j = gid; j < 32 * 32; j += stride) {
        const int o = j >> 5;
        const int i = j & 31;
        fc2wT[j] = fc2w[i * 32 + o];
    }
}

// ---- fused kernel ---------------------------------------------------------
// block = 256 thr = 4 waves = 4 boards; lane owns cols [4*lane, 4*lane+4).
__global__ void nnue_fwd_q8(
    const int*    __restrict__ wfeat,
    const float*  __restrict__ wval,
    const int*    __restrict__ bfeat,
    const float*  __restrict__ bval,
    const unsigned char* __restrict__ q8,   // [FEATSZ][256]
    const float4* __restrict__ ftb,         // [64] float4
    const __half* __restrict__ fc1wT,       // [32][512] fp16
    const float*  __restrict__ fc1b,
    const float*  __restrict__ fc2wT,       // [32][32] transposed
    const float*  __restrict__ fc2b,
    const float*  __restrict__ fc3w,        // [32]
    const float*  __restrict__ fc3b,
    float*        __restrict__ out)
{
    __shared__ float x[4][2 * HIDDEN];
    __shared__ float p1[4][2][32];
    __shared__ float h1[4][32];
    __shared__ float h2[4][32];

    const int tid  = threadIdx.x;
    const int w    = tid >> 6;
    const int lane = tid & 63;
    const int board = __builtin_amdgcn_readfirstlane((int)(blockIdx.x << 2) + w);

    const int*   wip = wfeat + board * NNZPB;   // wave-uniform -> s_load
    const float* wvp = wval  + board * NNZPB;
    const int*   bip = bfeat + board * NNZPB;
    const float* bvp = bval  + board * NNZPB;

    const int hoff = lane * 4;                  // byte offset in 256-B row

    // ---- phase 1: issue ALL 64 table loads into register arrays ----
    unsigned Hw[NNZPB], Hb[NNZPB];
    #pragma unroll
    for (int k = 0; k < NNZPB; ++k) {
        const int fw = wip[k];
        const int fb = bip[k];
        Hw[k] = *reinterpret_cast<const unsigned*>(q8 + (size_t)fw * 256 + hoff);
        Hb[k] = *reinterpret_cast<const unsigned*>(q8 + (size_t)fb * 256 + hoff);
    }

    // ---- phase 2: decode + accumulate ----
    float4 accw = {0.f, 0.f, 0.f, 0.f};
    float4 accb = {0.f, 0.f, 0.f, 0.f};
    float  sumw = 0.f, sumb = 0.f;
    #pragma unroll
    for (int k = 0; k < NNZPB; ++k) {
        const float vw = wvp[k];
        const float vb = bvp[k];
        sumw += vw;
        sumb += vb;
        dec4(Hw[k], QS * vw, accw);
        dec4(Hb[k], QS * vb, accb);
    }

    // remove the +128 encoding bias exactly, add ft bias, crelu
    const float corw = 128.0f * QS * sumw;
    const float corb = 128.0f * QS * sumb;
    const float4 bias = ftb[lane];
    {
        float4 cw, cb;
        cw.x = crelu1(accw.x - corw + bias.x); cw.y = crelu1(accw.y - corw + bias.y);
        cw.z = crelu1(accw.z - corw + bias.z); cw.w = crelu1(accw.w - corw + bias.w);
        cb.x = crelu1(accb.x - corb + bias.x); cb.y = crelu1(accb.y - corb + bias.y);
        cb.z = crelu1(accb.z - corb + bias.z); cb.w = crelu1(accb.w - corb + bias.w);
        reinterpret_cast<float4*>(x[w])[lane]      = cw;
        reinterpret_cast<float4*>(x[w])[64 + lane] = cb;
    }
    __syncthreads();

    // fc1: thread (o = lane&31, h = lane>>5), weights contiguous fp16
    {
        const int o = lane & 31;
        const int h = lane >> 5;
        const float4* xr = reinterpret_cast<const float4*>(&x[w][h * HIDDEN]);
        const uint4*  wr = reinterpret_cast<const uint4*>(
            fc1wT + (o << 9) + (h << 8));
        float s = 0.0f;
        #pragma unroll 8
        for (int i4 = 0; i4 < 32; ++i4) {
            const uint4  wq = wr[i4];
            const float4 x0 = xr[2 * i4];
            const float4 x1 = xr[2 * i4 + 1];
            const float2 w0 = __half22float2(*reinterpret_cast<const __half2*>(&wq.x));
            const float2 w1 = __half22float2(*reinterpret_cast<const __half2*>(&wq.y));
            const float2 w2 = __half22float2(*reinterpret_cast<const __half2*>(&wq.z));
            const float2 w3 = __half22float2(*reinterpret_cast<const __half2*>(&wq.w));
            s = fmaf(x0.x, w0.x, s); s = fmaf(x0.y, w0.y, s);
            s = fmaf(x0.z, w1.x, s); s = fmaf(x0.w, w1.y, s);
            s = fmaf(x1.x, w2.x, s); s = fmaf(x1.y, w2.y, s);
            s = fmaf(x1.z, w3.x, s); s = fmaf(x1.w, w3.y, s);
        }
        p1[w][h][o] = s;
    }
    __syncthreads();

    if (lane < 32) {
        const float v = p1[w][0][lane] + p1[w][1][lane] + fc1b[lane];
        h1[w][lane] = crelu1(v);
    }
    __syncthreads();

    if (lane < 32) {
        const float4* w2 = reinterpret_cast<const float4*>(fc2wT + (lane << 5));
        float s = fc2b[lane];
        #pragma unroll
        for (int i4 = 0; i4 < 8; ++i4) {
            const float4 wq = w2[i4];
            s = fmaf(h1[w][4 * i4 + 0], wq.x, s);
            s = fmaf(h1[w][4 * i4 + 1], wq.y, s);
            s = fmaf(h1[w][4 * i4 + 2], wq.z, s);
            s = fmaf(h1[w][4 * i4 + 3], wq.w, s);
        }
        h2[w][lane] = crelu1(s);
    }
    __syncthreads();

    if (lane == 0) {
        float s = fc3b[0];
        #pragma unroll
        for (int i = 0; i < 32; ++i)
            s = fmaf(h2[w][i], fc3w[i], s);
        out[board] = s;
    }
}

// ---- fallback: fully f32 fused (no workspace needed) --------------------
__global__ __launch_bounds__(256) void nnue_fwd_f32(
    const int*    __restrict__ wfeat,
    const float*  __restrict__ wval,
    const int*    __restrict__ bfeat,
    const float*  __restrict__ bval,
    const float4* __restrict__ ftw,
    const float4* __restrict__ ftb,
    const float*  __restrict__ fc1w,
    const float*  __restrict__ fc1b,
    const float*  __restrict__ fc2w,
    const float*  __restrict__ fc2b,
    const float*  __restrict__ fc3w,
    const float*  __restrict__ fc3b,
    float*        __restrict__ out)
{
    __shared__ float x[4][512];
    __shared__ float p1[4][2][32];
    __shared__ float h1[4][32];
    __shared__ float h2[4][32];

    const int tid  = threadIdx.x;
    const int w    = tid >> 6;
    const int lane = tid & 63;
    const int board = __builtin_amdgcn_readfirstlane((int)(blockIdx.x << 2) + w);

    const int*   wip = wfeat + board * NNZPB;
    const float* wvp = wval  + board * NNZPB;
    const int*   bip = bfeat + board * NNZPB;
    const float* bvp = bval  + board * NNZPB;

    float4 accw = ftb[lane];
    float4 accb = accw;

    #pragma unroll
    for (int k = 0; k < NNZPB; ++k) {
        const int   fw = wip[k];
        const float vw = wvp[k];
        const int   fb = bip[k];
        const float vb = bvp[k];
        const float4 rw = ftw[fw * 64 + lane];
        const float4 rb = ftw[fb * 64 + lane];
        accw.x = fmaf(rw.x, vw, accw.x); accw.y = fmaf(rw.y, vw, accw.y);
        accw.z = fmaf(rw.z, vw, accw.z); accw.w = fmaf(rw.w, vw, accw.w);
        accb.x = fmaf(rb.x, vb, accb.x); accb.y = fmaf(rb.y, vb, accb.y);
        accb.z = fmaf(rb.z, vb, accb.z); accb.w = fmaf(rb.w, vb, accb.w);
    }

    {
        float4 cw, cb;
        cw.x = crelu1(accw.x); cw.y = crelu1(accw.y);
        cw.z = crelu1(accw.z); cw.w = crelu1(accw.w);
        cb.x = crelu1(accb.x); cb.y = crelu1(accb.y);
        cb.z = crelu1(accb.z); cb.w = crelu1(accb.w);
        reinterpret_cast<float4*>(x[w])[lane]      = cw;
        reinterpret_cast<float4*>(x[w])[64 + lane] = cb;
    }
    __syncthreads();

    {
        const int o = lane & 31;
        const int h = lane >> 5;
        const float4* xr = reinterpret_cast<const float4*>(&x[w][h * 256]);
        const float*  wr = fc1w + (h * 256) * 32 + o;
        float s = 0.0f;
        #pragma unroll 16
        for (int i4 = 0; i4 < 64; ++i4) {
            const float4 xv = xr[i4];
            s = fmaf(xv.x, wr[(i4 * 4 + 0) * 32], s);
            s = fmaf(xv.y, wr[(i4 * 4 + 1) * 32], s);
            s = fmaf(xv.z, wr[(i4 * 4 + 2) * 32], s);
            s = fmaf(xv.w, wr[(i4 * 4 + 3) * 32], s);
        }
        p1[w][h][o] = s;
    }
    __syncthreads();

    if (lane < 32) {
        const float v = p1[w][0][lane] + p1[w][1][lane] + fc1b[lane];
        h1[w][lane] = crelu1(v);
    }
    __syncthreads();

    if (lane < 32) {
        float s = fc2b[lane];
        #pragma unroll
        for (int i = 0; i < 32; ++i)
            s = fmaf(h1[w][i], fc2w[i * 32 + lane], s);
        h2[w][lane] = crelu1(s);
    }
    __syncthreads();

    if (lane == 0) {
        float s = fc3b[0];
        #pragma unroll
        for (int i = 0; i < 32; ++i)
            s = fmaf(h2[w][i], fc3w[i], s);
        out[board] = s;
    }
}

extern "C" void kernel_launch(void* const* d_in, const int* in_sizes, int n_in,
                              void* d_out, int out_size, void* d_ws, size_t ws_size,
                              hipStream_t stream) {
    const int*   w_indices = (const int*)  d_in[0];
    const float* w_values  = (const float*)d_in[1];
    const int*   b_indices = (const int*)  d_in[2];
    const float* b_values  = (const float*)d_in[3];
    const float* ft_w      = (const float*)d_in[4];
    const float* ft_b      = (const float*)d_in[5];
    const float* fc1_w     = (const float*)d_in[6];
    const float* fc1_b     = (const float*)d_in[7];
    const float* fc2_w     = (const float*)d_in[8];
    const float* fc2_b     = (const float*)d_in[9];
    const float* fc3_w     = (const float*)d_in[10];
    const float* fc3_b     = (const float*)d_in[11];
    float* out = (float*)d_out;

    const int* wfeat = w_indices + NNZ;
    const int* bfeat = b_indices + NNZ;

    if (ws_size >= WS_NEED) {
        unsigned char* q8 = (unsigned char*)d_ws;
        __half* fc1wT     = (__half*)(q8 + Q8_BYTES);
        float*  fc2wT     = (float*)(q8 + Q8_BYTES + FC1T_BYTES);

        convert_q8<<<2048, 256, 0, stream>>>(
            (const float4*)ft_w, (unsigned int*)q8,
            fc1_w, fc1wT, fc2_w, fc2wT,
            FEATSZ * HIDDEN / 4);

        nnue_fwd_q8<<<BATCH / 4, 256, 0, stream>>>(
            wfeat, w_values, bfeat, b_values,
            q8, (const float4*)ft_b,
            fc1wT, fc1_b, fc2wT, fc2_b, fc3_w, fc3_b, out);
    } else {
        nnue_fwd_f32<<<BATCH / 4, 256, 0, stream>>>(
            wfeat, w_values, bfeat, b_values,
            (const float4*)ft_w, (const float4*)ft_b,
            fc1_w, fc1_b, fc2_w, fc2_b, fc3_w, fc3_b, out);
    }
}

// Round 14
// 67.745 us; speedup vs baseline: 1.5760x; 1.4277x over previous
//
#include <hip/hip_runtime.h>
#include <hip/hip_fp16.h>

// NNUE forward, R14: R10 gather (verbatim, 62us proven) + fc1 weights in LDS.
// R13 post-mortem: R12/R13's regression was the transposed-fc1-from-global
// pattern -- one uint4 load per wave touched 64 distinct cache lines (every
// lane its own line), 32 instr x 64 = 2048 line-events/board vs R10's 512.
// Line-event model (~3 cy/line/CU) fits R1/R3/R10. Fix: fc1 weights staged
// into LDS once per block (32KB fp16, XOR-swizzled vs bank conflicts),
// fc1 reads via ds_read_b128 -> ZERO VMEM line-events in fc1; staging adds
// only 128 line-events/board (512/block / 4 boards, L2-served).
// Gather untouched from R10. fc2 transposed-global (tiny). Single dispatch.

constexpr int BATCH  = 16384;
constexpr int NNZPB  = 32;
constexpr int NNZ    = BATCH * NNZPB;
constexpr int HIDDEN = 256;
constexpr int FEATSZ = 64 * 64 * 10;                      // 40960

constexpr float QLIM  = 0.0060329f;
constexpr float QS    = QLIM / 127.0f;
constexpr float QSINV = 127.0f / QLIM;

constexpr size_t Q8_BYTES   = (size_t)FEATSZ * 256;       // 10,485,760
constexpr size_t FC1T_BYTES = 512 * 32 * 2;               // 32,768
constexpr size_t FC2T_BYTES = 32 * 32 * 4;                // 4,096
constexpr size_t WS_NEED    = Q8_BYTES + FC1T_BYTES + FC2T_BYTES;

__device__ __forceinline__ float crelu1(float v) {
    return fminf(fmaxf(v, 0.0f), 1.0f);
}

// ---- convert: ft_w -> u8(+128); fc1_w -> fp16 T; fc2_w -> f32 T ----------
__global__ __launch_bounds__(256) void convert_q8(
    const float4* __restrict__ src,
    unsigned int* __restrict__ q8,
    const float*  __restrict__ fc1w,     // [512][32]
    __half*       __restrict__ fc1wT,    // [32][512] fp16
    const float*  __restrict__ fc2w,     // [32][32]
    float*        __restrict__ fc2wT,    // [32][32] transposed
    int n4)
{
    const int gid    = blockIdx.x * 256 + threadIdx.x;
    const int stride = gridDim.x * 256;
    for (int i = gid; i < n4; i += stride) {
        const float4 v = src[i];
        int q0 = (int)lrintf(v.x * QSINV) + 128;
        int q1 = (int)lrintf(v.y * QSINV) + 128;
        int q2 = (int)lrintf(v.z * QSINV) + 128;
        int q3 = (int)lrintf(v.w * QSINV) + 128;
        q0 = min(max(q0, 0), 255); q1 = min(max(q1, 0), 255);
        q2 = min(max(q2, 0), 255); q3 = min(max(q3, 0), 255);
        q8[i] = (unsigned)q0 | ((unsigned)q1 << 8) |
                ((unsigned)q2 << 16) | ((unsigned)q3 << 24);
    }
    for (int j = gid; j < 512 * 32; j += stride) {
        const int o = j >> 9;
        const int i = j & 511;
        fc1wT[j] = __float2half(fc1w[i * 32 + o]);
    }
    for (int j = gid; j < 32 * 32; j += stride) {
        const int o = j >> 5;
        const int i = j & 31;
        fc2wT[j] = fc2w[i * 32 + o];
    }
}

// ---- fused kernel ---------------------------------------------------------
// block = 256 thr = 4 waves = 4 boards; lane owns cols [4*lane, 4*lane+4).
__global__ void nnue_fwd_q8(
    const int*    __restrict__ wfeat,
    const float*  __restrict__ wval,
    const int*    __restrict__ bfeat,
    const float*  __restrict__ bval,
    const unsigned char* __restrict__ q8,   // [FEATSZ][256]
    const float4* __restrict__ ftb,         // [64] float4
    const __half* __restrict__ fc1wT,       // [32][512] fp16
    const float*  __restrict__ fc1b,
    const float*  __restrict__ fc2wT,       // [32][32] transposed
    const float*  __restrict__ fc2b,
    const float*  __restrict__ fc3w,        // [32]
    const float*  __restrict__ fc3b,
    float*        __restrict__ out)
{
    __shared__ float x[4][2 * HIDDEN];
    __shared__ float p1[4][2][32];
    __shared__ float h1[4][32];
    __shared__ float h2[4][32];
    __shared__ __align__(16) unsigned char wlds[32768];  // fc1wT, swizzled

    const int tid  = threadIdx.x;
    const int w    = tid >> 6;
    const int lane = tid & 63;
    const int board = __builtin_amdgcn_readfirstlane((int)(blockIdx.x << 2) + w);

    // ---- stage fc1wT into LDS (once per block), XOR swizzle -------------
    // chunk j (16B): row o = j>>6; lds byte = j*16 ^ ((o&15)<<4).
    // Swizzle flips bits 4-7 only -> bijective within each 256B group.
    {
        const uint4* srcw = reinterpret_cast<const uint4*>(fc1wT);
        #pragma unroll
        for (int k = 0; k < 8; ++k) {
            const int j = k * 256 + tid;
            const uint4 v = srcw[j];
            const int o = j >> 6;
            const int byte = (j * 16) ^ ((o & 15) << 4);
            *reinterpret_cast<uint4*>(wlds + byte) = v;
        }
    }

    const int*   wip = wfeat + board * NNZPB;   // wave-uniform -> s_load
    const float* wvp = wval  + board * NNZPB;
    const int*   bip = bfeat + board * NNZPB;
    const float* bvp = bval  + board * NNZPB;

    const int hoff = lane * 4;                  // dword offset in 256-B row

    float4 accw = {0.f, 0.f, 0.f, 0.f};
    float4 accb = {0.f, 0.f, 0.f, 0.f};
    float  sumw = 0.f, sumb = 0.f;

    // ---- gather: R10 verbatim ----
    #pragma unroll
    for (int k = 0; k < NNZPB; ++k) {
        const int   fw = wip[k];
        const float vw = wvp[k];
        const int   fb = bip[k];
        const float vb = bvp[k];
        const unsigned Hw = *reinterpret_cast<const unsigned*>(
            q8 + (size_t)fw * 256 + hoff);
        const unsigned Hb = *reinterpret_cast<const unsigned*>(
            q8 + (size_t)fb * 256 + hoff);

        const float svw = QS * vw;
        const float svb = QS * vb;
        sumw += vw;
        sumb += vb;

        accw.x = fmaf((float)(Hw & 0xFFu),         svw, accw.x);
        accw.y = fmaf((float)((Hw >> 8) & 0xFFu),  svw, accw.y);
        accw.z = fmaf((float)((Hw >> 16) & 0xFFu), svw, accw.z);
        accw.w = fmaf((float)(Hw >> 24),           svw, accw.w);
        accb.x = fmaf((float)(Hb & 0xFFu),         svb, accb.x);
        accb.y = fmaf((float)((Hb >> 8) & 0xFFu),  svb, accb.y);
        accb.z = fmaf((float)((Hb >> 16) & 0xFFu), svb, accb.z);
        accb.w = fmaf((float)(Hb >> 24),           svb, accb.w);
    }

    // remove the +128 encoding bias exactly, add ft bias, crelu
    const float corw = 128.0f * QS * sumw;
    const float corb = 128.0f * QS * sumb;
    const float4 bias = ftb[lane];
    {
        float4 cw, cb;
        cw.x = crelu1(accw.x - corw + bias.x); cw.y = crelu1(accw.y - corw + bias.y);
        cw.z = crelu1(accw.z - corw + bias.z); cw.w = crelu1(accw.w - corw + bias.w);
        cb.x = crelu1(accb.x - corb + bias.x); cb.y = crelu1(accb.y - corb + bias.y);
        cb.z = crelu1(accb.z - corb + bias.z); cb.w = crelu1(accb.w - corb + bias.w);
        reinterpret_cast<float4*>(x[w])[lane]      = cw;
        reinterpret_cast<float4*>(x[w])[64 + lane] = cb;
    }
    __syncthreads();   // covers x stores AND wlds staging

    // fc1: thread (o = lane&31, h = lane>>5); weights from LDS (swizzled),
    // 32 x ds_read_b128, zero VMEM.
    {
        const int o = lane & 31;
        const int h = lane >> 5;
        const float4* xr = reinterpret_cast<const float4*>(&x[w][h * HIDDEN]);
        const int wbase = (o << 10) + (h << 9);   // byte base of (o,h) region
        const int swz   = (o & 15) << 4;
        float s = 0.0f;
        #pragma unroll 8
        for (int i4 = 0; i4 < 32; ++i4) {
            const uint4 wq = *reinterpret_cast<const uint4*>(
                wlds + (wbase + ((i4 * 16) ^ swz)));
            const float4 x0 = xr[2 * i4];
            const float4 x1 = xr[2 * i4 + 1];
            const float2 w0 = __half22float2(*reinterpret_cast<const __half2*>(&wq.x));
            const float2 w1 = __half22float2(*reinterpret_cast<const __half2*>(&wq.y));
            const float2 w2 = __half22float2(*reinterpret_cast<const __half2*>(&wq.z));
            const float2 w3 = __half22float2(*reinterpret_cast<const __half2*>(&wq.w));
            s = fmaf(x0.x, w0.x, s); s = fmaf(x0.y, w0.y, s);
            s = fmaf(x0.z, w1.x, s); s = fmaf(x0.w, w1.y, s);
            s = fmaf(x1.x, w2.x, s); s = fmaf(x1.y, w2.y, s);
            s = fmaf(x1.z, w3.x, s); s = fmaf(x1.w, w3.y, s);
        }
        p1[w][h][o] = s;
    }
    __syncthreads();

    if (lane < 32) {
        const float v = p1[w][0][lane] + p1[w][1][lane] + fc1b[lane];
        h1[w][lane] = crelu1(v);
    }
    __syncthreads();

    // fc2: transposed, contiguous float4 from global (tiny, L1-resident)
    if (lane < 32) {
        const float4* w2 = reinterpret_cast<const float4*>(fc2wT + (lane << 5));
        float s = fc2b[lane];
        #pragma unroll
        for (int i4 = 0; i4 < 8; ++i4) {
            const float4 wq = w2[i4];
            s = fmaf(h1[w][4 * i4 + 0], wq.x, s);
            s = fmaf(h1[w][4 * i4 + 1], wq.y, s);
            s = fmaf(h1[w][4 * i4 + 2], wq.z, s);
            s = fmaf(h1[w][4 * i4 + 3], wq.w, s);
        }
        h2[w][lane] = crelu1(s);
    }
    __syncthreads();

    if (lane == 0) {
        float s = fc3b[0];
        #pragma unroll
        for (int i = 0; i < 32; ++i)
            s = fmaf(h2[w][i], fc3w[i], s);
        out[board] = s;
    }
}

// ---- fallback: fully f32 fused (no workspace needed) --------------------
__global__ __launch_bounds__(256) void nnue_fwd_f32(
    const int*    __restrict__ wfeat,
    const float*  __restrict__ wval,
    const int*    __restrict__ bfeat,
    const float*  __restrict__ bval,
    const float4* __restrict__ ftw,
    const float4* __restrict__ ftb,
    const float*  __restrict__ fc1w,
    const float*  __restrict__ fc1b,
    const float*  __restrict__ fc2w,
    const float*  __restrict__ fc2b,
    const float*  __restrict__ fc3w,
    const float*  __restrict__ fc3b,
    float*        __restrict__ out)
{
    __shared__ float x[4][512];
    __shared__ float p1[4][2][32];
    __shared__ float h1[4][32];
    __shared__ float h2[4][32];

    const int tid  = threadIdx.x;
    const int w    = tid >> 6;
    const int lane = tid & 63;
    const int board = __builtin_amdgcn_readfirstlane((int)(blockIdx.x << 2) + w);

    const int*   wip = wfeat + board * NNZPB;
    const float* wvp = wval  + board * NNZPB;
    const int*   bip = bfeat + board * NNZPB;
    const float* bvp = bval  + board * NNZPB;

    float4 accw = ftb[lane];
    float4 accb = accw;

    #pragma unroll
    for (int k = 0; k < NNZPB; ++k) {
        const int   fw = wip[k];
        const float vw = wvp[k];
        const int   fb = bip[k];
        const float vb = bvp[k];
        const float4 rw = ftw[fw * 64 + lane];
        const float4 rb = ftw[fb * 64 + lane];
        accw.x = fmaf(rw.x, vw, accw.x); accw.y = fmaf(rw.y, vw, accw.y);
        accw.z = fmaf(rw.z, vw, accw.z); accw.w = fmaf(rw.w, vw, accw.w);
        accb.x = fmaf(rb.x, vb, accb.x); accb.y = fmaf(rb.y, vb, accb.y);
        accb.z = fmaf(rb.z, vb, accb.z); accb.w = fmaf(rb.w, vb, accb.w);
    }

    {
        float4 cw, cb;
        cw.x = crelu1(accw.x); cw.y = crelu1(accw.y);
        cw.z = crelu1(accw.z); cw.w = crelu1(accw.w);
        cb.x = crelu1(accb.x); cb.y = crelu1(accb.y);
        cb.z = crelu1(accb.z); cb.w = crelu1(accb.w);
        reinterpret_cast<float4*>(x[w])[lane]      = cw;
        reinterpret_cast<float4*>(x[w])[64 + lane] = cb;
    }
    __syncthreads();

    {
        const int o = lane & 31;
        const int h = lane >> 5;
        const float4* xr = reinterpret_cast<const float4*>(&x[w][h * 256]);
        const float*  wr = fc1w + (h * 256) * 32 + o;
        float s = 0.0f;
        #pragma unroll 16
        for (int i4 = 0; i4 < 64; ++i4) {
            const float4 xv = xr[i4];
            s = fmaf(xv.x, wr[(i4 * 4 + 0) * 32], s);
            s = fmaf(xv.y, wr[(i4 * 4 + 1) * 32], s);
            s = fmaf(xv.z, wr[(i4 * 4 + 2) * 32], s);
            s = fmaf(xv.w, wr[(i4 * 4 + 3) * 32], s);
        }
        p1[w][h][o] = s;
    }
    __syncthreads();

    if (lane < 32) {
        const float v = p1[w][0][lane] + p1[w][1][lane] + fc1b[lane];
        h1[w][lane] = crelu1(v);
    }
    __syncthreads();

    if (lane < 32) {
        float s = fc2b[lane];
        #pragma unroll
        for (int i = 0; i < 32; ++i)
            s = fmaf(h1[w][i], fc2w[i * 32 + lane], s);
        h2[w][lane] = crelu1(s);
    }
    __syncthreads();

    if (lane == 0) {
        float s = fc3b[0];
        #pragma unroll
        for (int i = 0; i < 32; ++i)
            s = fmaf(h2[w][i], fc3w[i], s);
        out[board] = s;
    }
}

extern "C" void kernel_launch(void* const* d_in, const int* in_sizes, int n_in,
                              void* d_out, int out_size, void* d_ws, size_t ws_size,
                              hipStream_t stream) {
    const int*   w_indices = (const int*)  d_in[0];
    const float* w_values  = (const float*)d_in[1];
    const int*   b_indices = (const int*)  d_in[2];
    const float* b_values  = (const float*)d_in[3];
    const float* ft_w      = (const float*)d_in[4];
    const float* ft_b      = (const float*)d_in[5];
    const float* fc1_w     = (const float*)d_in[6];
    const float* fc1_b     = (const float*)d_in[7];
    const float* fc2_w     = (const float*)d_in[8];
    const float* fc2_b     = (const float*)d_in[9];
    const float* fc3_w     = (const float*)d_in[10];
    const float* fc3_b     = (const float*)d_in[11];
    float* out = (float*)d_out;

    const int* wfeat = w_indices + NNZ;
    const int* bfeat = b_indices + NNZ;

    if (ws_size >= WS_NEED) {
        unsigned char* q8 = (unsigned char*)d_ws;
        __half* fc1wT     = (__half*)(q8 + Q8_BYTES);
        float*  fc2wT     = (float*)(q8 + Q8_BYTES + FC1T_BYTES);

        convert_q8<<<2048, 256, 0, stream>>>(
            (const float4*)ft_w, (unsigned int*)q8,
            fc1_w, fc1wT, fc2_w, fc2wT,
            FEATSZ * HIDDEN / 4);

        nnue_fwd_q8<<<BATCH / 4, 256, 0, stream>>>(
            wfeat, w_values, bfeat, b_values,
            q8, (const float4*)ft_b,
            fc1wT, fc1_b, fc2wT, fc2_b, fc3_w, fc3_b, out);
    } else {
        nnue_fwd_f32<<<BATCH / 4, 256, 0, stream>>>(
            wfeat, w_values, bfeat, b_values,
            (const float4*)ft_w, (const float4*)ft_b,
            fc1_w, fc1_b, fc2_w, fc2_b, fc3_w, fc3_b, out);
    }
}